// Round 3
// baseline (22.959 us; speedup 1.0000x reference)
//
#include <hip/hip_runtime.h>
#include <hip/hip_bf16.h>

// B=16, N=100, D=256, C=2, E=N*(N-1)=9900.
// Complete-graph GCN collapses to a per-batch MLP:
//   gcn_conv(x) = mean_n(x) @ W + b  (deg==100, norm==1/100, incl. self-loop)
// R2: the R1 single-block-per-batch MLP was per-CU-BW-bound (~1MB weights
// through one CU's L2 port). Split into per-layer kernels, 128 blocks each,
// so weight traffic spreads across 128 CUs. Out-kernel computes log_softmax
// per block (redundant, cheap) to avoid a 5th tiny launch.

#define BB 16
#define NN 100
#define DD 256
#define EE 9900

// ws float offsets
#define WS_XB 0
#define WS_Z1 4096
#define WS_Z2 8192
#define WS_H  12288

// ---- K0: xbar[b][d] = mean_n x[b][n][d] ----
// grid 128 = (16 b) x (8 d-chunks of 32); 256 thr = 32 dl x 8 node-groups.
__global__ __launch_bounds__(256) void k_xbar(
    const float* __restrict__ x, float* __restrict__ ws)
{
    const int b  = blockIdx.x >> 3;
    const int d0 = (blockIdx.x & 7) * 32;
    const int dl = threadIdx.x & 31;
    const int w  = threadIdx.x >> 5;          // node group 0..7

    __shared__ float sP[8][32];

    // 100 nodes: groups 0..3 take 13, groups 4..7 take 12
    const int start = w * 12 + (w < 4 ? w : 4);
    const int cnt   = 12 + (w < 4 ? 1 : 0);

    const float* xp = x + ((size_t)b * NN + start) * DD + d0 + dl;
    float acc = 0.f;
    #pragma unroll
    for (int i = 0; i < 13; ++i)
        if (i < cnt) acc += xp[i * DD];
    sP[w][dl] = acc;
    __syncthreads();
    if (threadIdx.x < 32) {
        float s = 0.f;
        #pragma unroll
        for (int g = 0; g < 8; ++g) s += sP[g][dl];
        ws[WS_XB + b * DD + d0 + dl] = s * 0.01f;
    }
}

// ---- K1/K2: out[b][d] = relu(in[b] @ W + bias) ----
// grid 128 = (16 b) x (8 d-chunks of 32); 256 thr = 32 dl x 8 k-groups of 32.
__global__ __launch_bounds__(256) void k_layer(
    const float* __restrict__ ws_in, const float* __restrict__ W,
    const float* __restrict__ bias, float* __restrict__ ws_out)
{
    const int b  = blockIdx.x >> 3;
    const int d0 = (blockIdx.x & 7) * 32;
    const int dl = threadIdx.x & 31;
    const int w  = threadIdx.x >> 5;          // k group

    __shared__ float sA[DD];
    __shared__ float sP[8][32];

    sA[threadIdx.x] = ws_in[b * DD + threadIdx.x];
    __syncthreads();

    const float* Wp = W + (size_t)(w * 32) * DD + d0 + dl;
    const float* ak = sA + w * 32;
    float acc = 0.f;
    #pragma unroll
    for (int k = 0; k < 32; ++k)
        acc = fmaf(ak[k], Wp[k * DD], acc);
    sP[w][dl] = acc;
    __syncthreads();
    if (threadIdx.x < 32) {
        float s = bias[d0 + dl];
        #pragma unroll
        for (int g = 0; g < 8; ++g) s += sP[g][dl];
        ws_out[b * DD + d0 + dl] = fmaxf(s, 0.f);
    }
}

// ---- K3: h[b][d] = relu(z2[b] @ (Wl1[:D]+Wl1[D:]) + bl1) ----
__global__ __launch_bounds__(256) void k_layer3(
    const float* __restrict__ ws_in, const float* __restrict__ Wl1,
    const float* __restrict__ bias, float* __restrict__ ws_out)
{
    const int b  = blockIdx.x >> 3;
    const int d0 = (blockIdx.x & 7) * 32;
    const int dl = threadIdx.x & 31;
    const int w  = threadIdx.x >> 5;

    __shared__ float sA[DD];
    __shared__ float sP[8][32];

    sA[threadIdx.x] = ws_in[b * DD + threadIdx.x];
    __syncthreads();

    const float* Wp0 = Wl1 + (size_t)(w * 32) * DD + d0 + dl;
    const float* Wp1 = Wl1 + (size_t)(w * 32 + DD) * DD + d0 + dl;
    const float* ak = sA + w * 32;
    float acc = 0.f;
    #pragma unroll
    for (int k = 0; k < 32; ++k)
        acc = fmaf(ak[k], Wp0[k * DD] + Wp1[k * DD], acc);
    sP[w][dl] = acc;
    __syncthreads();
    if (threadIdx.x < 32) {
        float s = bias[d0 + dl];
        #pragma unroll
        for (int g = 0; g < 8; ++g) s += sP[g][dl];
        ws_out[b * DD + d0 + dl] = fmaxf(s, 0.f);
    }
}

// ---- K_out: per-block redundant logits+log_softmax, then coalesced writes ----
// grid (39 e-chunks, 16 b); 256 thr.
__global__ __launch_bounds__(256) void k_out(
    const float* __restrict__ bboxes,   // [B,N,4]
    const int*   __restrict__ edge,     // [2,E]
    const float* __restrict__ ws,       // h at WS_H
    const float* __restrict__ Wf, const float* __restrict__ bf,
    float* __restrict__ out)
{
    const int b  = blockIdx.y;
    const int e0 = blockIdx.x * 256;
    const int t  = threadIdx.x;

    __shared__ float r0[4], r1[4];
    __shared__ float sp0, sp1;

    // logits: dot(h[b], Wf[:,c]) over 256 threads
    float hv = ws[WS_H + b * DD + t];
    float l0 = hv * Wf[t * 2 + 0];
    float l1 = hv * Wf[t * 2 + 1];
    #pragma unroll
    for (int off = 32; off > 0; off >>= 1) {
        l0 += __shfl_down(l0, off, 64);
        l1 += __shfl_down(l1, off, 64);
    }
    if ((t & 63) == 0) { r0[t >> 6] = l0; r1[t >> 6] = l1; }
    __syncthreads();
    if (t == 0) {
        float L0 = r0[0] + r0[1] + r0[2] + r0[3] + bf[0];
        float L1 = r1[0] + r1[1] + r1[2] + r1[3] + bf[1];
        float m  = fmaxf(L0, L1);
        float ls = logf(expf(L0 - m) + expf(L1 - m));
        sp0 = L0 - m - ls;
        sp1 = L1 - m - ls;
    }
    __syncthreads();

    const int e = e0 + t;
    if (e >= EE) return;

    const int idx = b * EE + e;
    const int s   = edge[e];
    const int dd  = edge[EE + e];

    float2 p; p.x = sp0; p.y = sp1;
    reinterpret_cast<float2*>(out)[idx] = p;

    const float4 bs = *reinterpret_cast<const float4*>(bboxes + (size_t)(b * NN + s) * 4);
    const float4 bd = *reinterpret_cast<const float4*>(bboxes + (size_t)(b * NN + dd) * 4);
    float4* bout = reinterpret_cast<float4*>(out + (size_t)BB * EE * 2);
    bout[idx * 2 + 0] = bs;
    bout[idx * 2 + 1] = bd;
}

extern "C" void kernel_launch(void* const* d_in, const int* in_sizes, int n_in,
                              void* d_out, int out_size, void* d_ws, size_t ws_size,
                              hipStream_t stream) {
    const float* hidden  = (const float*)d_in[0];
    const float* bboxes  = (const float*)d_in[1];
    const float* W1      = (const float*)d_in[2];
    const float* b1      = (const float*)d_in[3];
    const float* W2      = (const float*)d_in[4];
    const float* b2      = (const float*)d_in[5];
    const float* Wl1     = (const float*)d_in[6];
    const float* bl1     = (const float*)d_in[7];
    const float* Wf      = (const float*)d_in[8];
    const float* bf      = (const float*)d_in[9];
    const int*   edge    = (const int*)d_in[10];

    float* ws  = (float*)d_ws;
    float* out = (float*)d_out;

    k_xbar  <<<128, 256, 0, stream>>>(hidden, ws);
    k_layer <<<128, 256, 0, stream>>>(ws + WS_XB, W1, b1, ws + WS_Z1);
    k_layer <<<128, 256, 0, stream>>>(ws + WS_Z1, W2, b2, ws + WS_Z2);
    k_layer3<<<128, 256, 0, stream>>>(ws + WS_Z2, Wl1, bl1, ws + WS_H);

    dim3 og(39, 16);
    k_out<<<og, 256, 0, stream>>>(bboxes, edge, ws, Wf, bf, out);
}

// Round 4
// 16.512 us; speedup vs baseline: 1.3904x; 1.3904x over previous
//
#include <hip/hip_runtime.h>
#include <hip/hip_bf16.h>

// B=16, N=100, D=256, C=2, E=N*(N-1)=9900.
// Complete-graph GCN collapses to a per-batch MLP:
//   gcn_conv(x) = mean_n(x) @ W + b  (deg==100, norm==1/100, incl. self-loop)
// R3: two kernels. k_mlp: grid (16 b x 8 g). Each block computes xbar and
// z1,z2 redundantly (per-CU 612KB incl. x[b]), but splits Wl1's columns 8
// ways (64KB/block) and emits per-slice partial logits. k_out assembles
// logits + log_softmax per block and does the coalesced broadcast/gather.
// Rationale: R2 showed ~1.3-3us fixed cost per dispatch -> minimize kernel
// count; R1 showed per-CU L2 BW (~135GB/s) limits -> minimize bytes/CU.

#define BB 16
#define NN 100
#define DD 256
#define EE 9900
#define GG 8            // Wl1 column-split factor

// ---- K1: fused MLP, one block per (batch, col-slice) ----
__global__ __launch_bounds__(256) void k_mlp(
    const float* __restrict__ x,    // [B,N,D]
    const float* __restrict__ W1, const float* __restrict__ b1,
    const float* __restrict__ W2, const float* __restrict__ b2,
    const float* __restrict__ Wl1, const float* __restrict__ bl1,
    const float* __restrict__ Wf,
    float* __restrict__ ws_l)       // [B][GG][2] partial logits
{
    const int b = blockIdx.x >> 3;
    const int g = blockIdx.x & 7;
    const int t = threadIdx.x;

    __shared__ __align__(16) float sX[DD];
    __shared__ __align__(16) float sY[DD];
    __shared__ float4 sP[256];      // reduction scratch
    __shared__ float sL[8][2];

    // ---- xbar[t] = mean_n x[b][n][t] ----
    {
        const float* xp = x + (size_t)b * NN * DD + t;
        float a0 = 0.f, a1 = 0.f, a2 = 0.f, a3 = 0.f;
        #pragma unroll
        for (int n = 0; n < NN; n += 4) {
            a0 += xp[(n + 0) * DD];
            a1 += xp[(n + 1) * DD];
            a2 += xp[(n + 2) * DD];
            a3 += xp[(n + 3) * DD];
        }
        sX[t] = (a0 + a1 + a2 + a3) * 0.01f;
    }
    __syncthreads();

    // ---- layer 1: sY = relu(sX @ W1 + b1), k-split 4 x col-quads ----
    {
        const int c4 = t & 63, kq = t >> 6;
        const float* Wp = W1 + (size_t)(kq * 64) * DD + 4 * c4;
        const float* xk = sX + kq * 64;
        float4 acc = {0.f, 0.f, 0.f, 0.f};
        #pragma unroll 8
        for (int k = 0; k < 64; ++k) {
            float4 w = *(const float4*)(Wp + (size_t)k * DD);
            float xv = xk[k];
            acc.x = fmaf(xv, w.x, acc.x); acc.y = fmaf(xv, w.y, acc.y);
            acc.z = fmaf(xv, w.z, acc.z); acc.w = fmaf(xv, w.w, acc.w);
        }
        sP[kq * 64 + c4] = acc;
        __syncthreads();
        if (t < 64) {
            float4 s0 = sP[t], s1 = sP[64 + t], s2 = sP[128 + t], s3 = sP[192 + t];
            float4 bs = *(const float4*)(b1 + 4 * t);
            float4 r;
            r.x = fmaxf(s0.x + s1.x + s2.x + s3.x + bs.x, 0.f);
            r.y = fmaxf(s0.y + s1.y + s2.y + s3.y + bs.y, 0.f);
            r.z = fmaxf(s0.z + s1.z + s2.z + s3.z + bs.z, 0.f);
            r.w = fmaxf(s0.w + s1.w + s2.w + s3.w + bs.w, 0.f);
            *(float4*)&sY[4 * t] = r;
        }
        __syncthreads();
    }

    // ---- layer 2: sX = relu(sY @ W2 + b2) ----
    {
        const int c4 = t & 63, kq = t >> 6;
        const float* Wp = W2 + (size_t)(kq * 64) * DD + 4 * c4;
        const float* xk = sY + kq * 64;
        float4 acc = {0.f, 0.f, 0.f, 0.f};
        #pragma unroll 8
        for (int k = 0; k < 64; ++k) {
            float4 w = *(const float4*)(Wp + (size_t)k * DD);
            float xv = xk[k];
            acc.x = fmaf(xv, w.x, acc.x); acc.y = fmaf(xv, w.y, acc.y);
            acc.z = fmaf(xv, w.z, acc.z); acc.w = fmaf(xv, w.w, acc.w);
        }
        sP[kq * 64 + c4] = acc;
        __syncthreads();
        if (t < 64) {
            float4 s0 = sP[t], s1 = sP[64 + t], s2 = sP[128 + t], s3 = sP[192 + t];
            float4 bs = *(const float4*)(b2 + 4 * t);
            float4 r;
            r.x = fmaxf(s0.x + s1.x + s2.x + s3.x + bs.x, 0.f);
            r.y = fmaxf(s0.y + s1.y + s2.y + s3.y + bs.y, 0.f);
            r.z = fmaxf(s0.z + s1.z + s2.z + s3.z + bs.z, 0.f);
            r.w = fmaxf(s0.w + s1.w + s2.w + s3.w + bs.w, 0.f);
            *(float4*)&sX[4 * t] = r;
        }
        __syncthreads();
    }

    // ---- layer 3 (this block's 32 cols): h = relu(z2 @ (Wl1_top+Wl1_bot) + bl1)
    //      + partial logits over those cols ----
    {
        const int c8 = t & 7;       // col quad within slice (8 quads = 32 cols)
        const int kq = t >> 3;      // 32 k-chunks of 8
        const float* Wp0 = Wl1 + (size_t)(kq * 8) * DD + g * 32 + 4 * c8;
        const float* Wp1 = Wp0 + (size_t)DD * DD;
        const float* xk = sX + kq * 8;
        float4 acc = {0.f, 0.f, 0.f, 0.f};
        #pragma unroll
        for (int k = 0; k < 8; ++k) {
            float4 w0 = *(const float4*)(Wp0 + (size_t)k * DD);
            float4 w1 = *(const float4*)(Wp1 + (size_t)k * DD);
            float xv = xk[k];
            acc.x = fmaf(xv, w0.x + w1.x, acc.x);
            acc.y = fmaf(xv, w0.y + w1.y, acc.y);
            acc.z = fmaf(xv, w0.z + w1.z, acc.z);
            acc.w = fmaf(xv, w0.w + w1.w, acc.w);
        }
        sP[kq * 8 + c8] = acc;
        __syncthreads();
        if (t < 8) {
            float4 s = {0.f, 0.f, 0.f, 0.f};
            #pragma unroll
            for (int q = 0; q < 32; ++q) {
                float4 p = sP[q * 8 + t];
                s.x += p.x; s.y += p.y; s.z += p.z; s.w += p.w;
            }
            const int c0 = g * 32 + 4 * t;  // global col of s.x
            float4 bs = *(const float4*)(bl1 + c0);
            float h0 = fmaxf(s.x + bs.x, 0.f);
            float h1 = fmaxf(s.y + bs.y, 0.f);
            float h2 = fmaxf(s.z + bs.z, 0.f);
            float h3 = fmaxf(s.w + bs.w, 0.f);
            float l0 = h0 * Wf[(c0 + 0) * 2] + h1 * Wf[(c0 + 1) * 2]
                     + h2 * Wf[(c0 + 2) * 2] + h3 * Wf[(c0 + 3) * 2];
            float l1 = h0 * Wf[(c0 + 0) * 2 + 1] + h1 * Wf[(c0 + 1) * 2 + 1]
                     + h2 * Wf[(c0 + 2) * 2 + 1] + h3 * Wf[(c0 + 3) * 2 + 1];
            sL[t][0] = l0;
            sL[t][1] = l1;
        }
        __syncthreads();
        if (t == 0) {
            float l0 = 0.f, l1 = 0.f;
            #pragma unroll
            for (int i = 0; i < 8; ++i) { l0 += sL[i][0]; l1 += sL[i][1]; }
            ws_l[(b * GG + g) * 2 + 0] = l0;
            ws_l[(b * GG + g) * 2 + 1] = l1;
        }
    }
}

// ---- K2: assemble logits + log_softmax per block, coalesced output writes ----
__global__ __launch_bounds__(256) void k_out(
    const float* __restrict__ bboxes,   // [B,N,4]
    const int*   __restrict__ edge,     // [2,E]
    const float* __restrict__ ws_l,     // [B][GG][2]
    const float* __restrict__ bf,
    float* __restrict__ out)
{
    const int b  = blockIdx.y;
    const int e0 = blockIdx.x * 256;
    const int t  = threadIdx.x;

    __shared__ float sp0, sp1;
    if (t == 0) {
        float L0 = bf[0], L1 = bf[1];
        #pragma unroll
        for (int g = 0; g < GG; ++g) {
            L0 += ws_l[(b * GG + g) * 2 + 0];
            L1 += ws_l[(b * GG + g) * 2 + 1];
        }
        float m  = fmaxf(L0, L1);
        float ls = logf(expf(L0 - m) + expf(L1 - m));
        sp0 = L0 - m - ls;
        sp1 = L1 - m - ls;
    }
    __syncthreads();

    const int e = e0 + t;
    if (e >= EE) return;

    const int idx = b * EE + e;
    const int s   = edge[e];
    const int dd  = edge[EE + e];

    float2 p; p.x = sp0; p.y = sp1;
    reinterpret_cast<float2*>(out)[idx] = p;

    const float4 bs = *reinterpret_cast<const float4*>(bboxes + (size_t)(b * NN + s) * 4);
    const float4 bd = *reinterpret_cast<const float4*>(bboxes + (size_t)(b * NN + dd) * 4);
    float4* bout = reinterpret_cast<float4*>(out + (size_t)BB * EE * 2);
    bout[idx * 2 + 0] = bs;
    bout[idx * 2 + 1] = bd;
}

extern "C" void kernel_launch(void* const* d_in, const int* in_sizes, int n_in,
                              void* d_out, int out_size, void* d_ws, size_t ws_size,
                              hipStream_t stream) {
    const float* hidden  = (const float*)d_in[0];
    const float* bboxes  = (const float*)d_in[1];
    const float* W1      = (const float*)d_in[2];
    const float* b1      = (const float*)d_in[3];
    const float* W2      = (const float*)d_in[4];
    const float* b2      = (const float*)d_in[5];
    const float* Wl1     = (const float*)d_in[6];
    const float* bl1     = (const float*)d_in[7];
    const float* Wf      = (const float*)d_in[8];
    const float* bf      = (const float*)d_in[9];
    const int*   edge    = (const int*)d_in[10];

    float* ws_l = (float*)d_ws;     // B*GG*2 floats
    float* out  = (float*)d_out;

    k_mlp<<<BB * GG, 256, 0, stream>>>(hidden, W1, b1, W2, b2,
                                       Wl1, bl1, Wf, ws_l);

    dim3 og((EE + 255) / 256, BB);
    k_out<<<og, 256, 0, stream>>>(bboxes, edge, ws_l, bf, out);
}